// Round 20
// baseline (75.895 us; speedup 1.0000x reference)
//
#include <hip/hip_runtime.h>
#include <hip/hip_bf16.h>

#define BB 128
#define NN 256
#define CC 192
#define HH 8
#define HD 24
#define NWIN 16

typedef __bf16 bf16x8 __attribute__((ext_vector_type(8)));
typedef float f32x4 __attribute__((ext_vector_type(4)));

#define QB_BYTES (size_t)(BB * HH * NN * HD * 2)    // 12,582,912 (unpadded)
#define AB_BYTES (size_t)(BB * NN * CC * 2)         // 12,582,912
#define BIASF_BYTES (size_t)((HH + NWIN) * NN * NN * 2)  // 3,145,728

#define L2E 1.4426950408889634f

// hardware bf16 converts (v_cvt_pk_bf16_f32 / scalar cvt)
__device__ inline unsigned int pkbf(float a, float b) {
    __hip_bfloat162 h = __float22bfloat162_rn(float2{a, b});
    return *reinterpret_cast<unsigned int*>(&h);
}
__device__ inline unsigned short sbf(float a) {
    __hip_bfloat16 h = __float2bfloat16(a);
    return *reinterpret_cast<unsigned short*>(&h);
}

// ---------------------------------------------------------------------------
// Kernel 1 (fused): blocks [0,2304) = qkv GEMM (r16 structure); [2304,2688) =
// fragment-ordered rel16/mask16 conversion (x log2e). r20: NO combined
// 16.8MB bias table -- rel (1MB) and mask (2MB) are stored separately,
// each fragment-ordered (U = w*32+kt*8+t*4+f, elem = (U*64+l)*4+jr), so
// attn's loads stay contiguous while the unique data is 3MB L2-resident.
// ---------------------------------------------------------------------------
#define XSTR 72    // 64 cols + 8 pad (144B rows; 2-way LDS aliasing = free)

__global__ __launch_bounds__(256) void qkv_bias_kernel(
    const float* __restrict__ x, const float* __restrict__ wq,
    const float* __restrict__ rel, const float* __restrict__ maskp,
    unsigned short* __restrict__ qb, unsigned short* __restrict__ kb,
    unsigned short* __restrict__ vt, unsigned short* __restrict__ biasf)
{
    __shared__ __align__(16) unsigned short Xs[128 * XSTR];  // 18432B (reused U/T)
    __shared__ __align__(16) unsigned short Ws[64 * XSTR];   // 9216B

    const int tid = threadIdx.x;
    const int wgid = blockIdx.x;

    if (wgid >= 2304) {
        // ---- convert branch: 393216 8B-units total (rel 131072, mask 262144)
        int idx0 = (wgid - 2304) * 256 + tid;      // [0, 98304)
        #pragma unroll
        for (int u = 0; u < 4; ++u) {
            int idx = idx0 + u * 98304;
            const float* src;
            int c, rem;
            if (idx < 131072) { c = idx >> 14; rem = idx & 16383; src = rel; }
            else { int im = idx - 131072; c = im >> 14; rem = im & 16383; src = maskp; }
            int U = rem >> 6;
            int l = rem & 63;
            int f = U & 3, t = (U >> 2) & 1, kt = (U >> 3) & 3, w2 = U >> 5;
            int q = w2 * 32 + t * 16 + (l & 15);
            int k0 = kt * 64 + ((f >> 1) << 5) + ((l >> 4) << 3) + ((f & 1) << 2);
            float4 v = *reinterpret_cast<const float4*>(
                src + ((size_t)c * NN + q) * NN + k0);
            uint2 o;
            o.x = pkbf(v.x * L2E, v.y * L2E);
            o.y = pkbf(v.z * L2E, v.w * L2E);
            *reinterpret_cast<uint2*>(biasf + (size_t)idx * 4) = o;
        }
        return;
    }

    // ---- qkv branch (r16 verbatim)
    const int q = wgid;                           // 2304 = 8 XCD * 288
    const int xcd = q & 7;
    const int j = q >> 3;
    const int bm = (xcd * 32 + (j & 31)) * 128;
    const int bn = (j >> 5) * 64;

    const int w = tid >> 6, l = tid & 63, lq = l & 15, g = l >> 4;
    const int wm = w >> 1, wn = w & 1;

    f32x4 acc[4][2];
    #pragma unroll
    for (int s = 0; s < 4; ++s)
        #pragma unroll
        for (int t = 0; t < 2; ++t)
            acc[s][t] = (f32x4){0.f, 0.f, 0.f, 0.f};

    #pragma unroll
    for (int kh = 0; kh < 3; ++kh) {
        // stage X (coalesced): 2048 float4/stage, 8/thread; 16 lanes per row
        #pragma unroll
        for (int i = 0; i < 8; ++i) {
            int idx = i * 256 + tid;
            int row = idx >> 4, c4 = idx & 15;
            float4 v = *reinterpret_cast<const float4*>(
                x + (size_t)(bm + row) * 192 + kh * 64 + c4 * 4);
            uint2 o;
            o.x = pkbf(v.x, v.y);
            o.y = pkbf(v.z, v.w);
            *reinterpret_cast<uint2*>(&Xs[row * XSTR + c4 * 4]) = o;
        }
        // stage W (coalesced): 1024 float4/stage, 4/thread
        #pragma unroll
        for (int i = 0; i < 4; ++i) {
            int idx = i * 256 + tid;
            int row = idx >> 4, c4 = idx & 15;
            float4 v = *reinterpret_cast<const float4*>(
                wq + (size_t)(bn + row) * 192 + kh * 64 + c4 * 4);
            uint2 o;
            o.x = pkbf(v.x, v.y);
            o.y = pkbf(v.z, v.w);
            *reinterpret_cast<uint2*>(&Ws[row * XSTR + c4 * 4]) = o;
        }
        __syncthreads();

        #pragma unroll
        for (int kk = 0; kk < 2; ++kk) {
            bf16x8 b0 = *reinterpret_cast<const bf16x8*>(
                &Ws[(wn * 32 + lq) * XSTR + kk * 32 + g * 8]);
            bf16x8 b1 = *reinterpret_cast<const bf16x8*>(
                &Ws[(wn * 32 + 16 + lq) * XSTR + kk * 32 + g * 8]);
            #pragma unroll
            for (int s = 0; s < 4; ++s) {
                bf16x8 a = *reinterpret_cast<const bf16x8*>(
                    &Xs[(wm * 64 + s * 16 + lq) * XSTR + kk * 32 + g * 8]);
                acc[s][0] = __builtin_amdgcn_mfma_f32_16x16x32_bf16(a, b0, acc[s][0], 0, 0, 0);
                acc[s][1] = __builtin_amdgcn_mfma_f32_16x16x32_bf16(a, b1, acc[s][1], 0, 0, 0);
            }
        }
        __syncthreads();   // done reading this stage (also guards Xs reuse)
    }

    const int t3 = bn / 192;          // tile is pure q (0), k (1) or v (2)
    const int bnm = bn - t3 * 192;    // 0, 64, 128
    const int bbi = bm >> 8;

    if (t3 < 2) {
        // ---- path A: U[m_local][c_local], stride 72 (fills Xs exactly)
        // q pre-scaled into exp2 domain: 24^-0.5 * log2(e)
        const float sc = (t3 == 0) ? 0.29448889f : 1.0f;
        #pragma unroll
        for (int s = 0; s < 4; ++s)
            #pragma unroll
            for (int t = 0; t < 2; ++t)
                #pragma unroll
                for (int jr = 0; jr < 4; ++jr) {
                    int ml = wm * 64 + s * 16 + g * 4 + jr;
                    int cl = wn * 32 + t * 16 + lq;
                    Xs[ml * 72 + cl] = sbf(acc[s][t][jr] * sc);
                }
        __syncthreads();
        unsigned short* dstb = (t3 == 0) ? qb : kb;
        #pragma unroll
        for (int i = 0; i < 8; ++i) {
            int idx = i * 256 + tid;
            int row = idx >> 4, quad = (idx & 15) * 4;
            int cg = bnm + quad;
            int h = cg / 24;
            int d = cg - h * 24;
            int m = bm + row;
            int n = m & 255;
            uint2 v = *reinterpret_cast<const uint2*>(&Xs[row * 72 + quad]);
            *reinterpret_cast<uint2*>(
                &dstb[(((size_t)(bbi * 8 + h) * 256) + n) * 24 + d]) = v;
        }
    } else {
        // ---- path B: T[c_local][m_local], stride 136 (8704 <= 9216 Xs)
        #pragma unroll
        for (int s = 0; s < 4; ++s)
            #pragma unroll
            for (int t = 0; t < 2; ++t) {
                int cl = wn * 32 + t * 16 + lq;
                int m0 = wm * 64 + s * 16 + g * 4;
                uint2 pk2;
                pk2.x = pkbf(acc[s][t][0], acc[s][t][1]);
                pk2.y = pkbf(acc[s][t][2], acc[s][t][3]);
                *reinterpret_cast<uint2*>(&Xs[cl * 136 + m0]) = pk2;
            }
        __syncthreads();
        const int n0 = bm & 255;
        #pragma unroll
        for (int i = 0; i < 4; ++i) {
            int idx = i * 256 + tid;
            int row = idx >> 4, q8 = (idx & 15) * 8;
            int cg = bnm + row;
            int h = cg / 24, d = cg - h * 24;
            uint4 v = *reinterpret_cast<const uint4*>(&Xs[row * 136 + q8]);
            *reinterpret_cast<uint4*>(
                &vt[((size_t)((bbi * 8 + h) * 24) + d) * 256 + n0 + q8]) = v;
        }
    }
}

// ---------------------------------------------------------------------------
// Kernel 2: flash MFMA attention, NO-MAX softmax. r20: C-init = rel + mask
// from the two fragment-ordered tables (contiguous wave loads, 3MB L2-hot).
// ---------------------------------------------------------------------------
#define KSTR 40
#define VSTR 264

__global__ __launch_bounds__(512) void attn_mfma_kernel(
    const unsigned short* __restrict__ qb, const unsigned short* __restrict__ kb,
    const unsigned short* __restrict__ vt,
    const unsigned short* __restrict__ biasf,
    unsigned short* __restrict__ ab)
{
    __shared__ __align__(16) unsigned short Kl[NN * KSTR];    // 20480 B (permuted)
    __shared__ __align__(16) unsigned short Vl[24 * VSTR];    // 12672 B

    const int tid = threadIdx.x;
    const int w  = tid >> 6;
    const int l  = tid & 63;
    const int lq = l & 15;
    const int g  = l >> 4;
    const int wgid = blockIdx.x;
    const int c = wgid & 127;          // combo = h*16 + wi (XCD-local)
    const int j = wgid >> 7;
    const int h = c >> 4;
    const int b = (c & 15) + (j << 4);
    const int wi = b & 15;

    const unsigned short* kp = kb + (size_t)(b * HH + h) * NN * HD;
    const unsigned short* vp = vt + (size_t)(b * HH + h) * HD * NN;
    const unsigned short* qp = qb + (size_t)(b * HH + h) * NN * HD;
    // fragment-ordered tables: rel at [h], mask at [8 + wi]; wave slice +w*8192
    const unsigned short* rpw = biasf + ((size_t)h << 16) + ((size_t)w << 13);
    const unsigned short* mpw = biasf + ((size_t)(HH + wi) << 16) + ((size_t)w << 13);

    // stage K permuted; d=24..31 chunk zero-filled (unpadded source)
    for (int i = tid; i < 1024; i += 512) {
        int r = i >> 2, cc = i & 3;
        int pr = ((r >> 5) << 5) + (((r >> 2) & 1) << 4) + (((r >> 3) & 3) << 2) + (r & 3);
        uint4 val = {0u, 0u, 0u, 0u};
        if (cc < 3)
            val = *reinterpret_cast<const uint4*>(kp + r * HD + cc * 8);
        *reinterpret_cast<uint4*>(&Kl[pr * KSTR + cc * 8]) = val;
    }
    // stage V^T rows 0..23 (natural order)
    for (int i = tid; i < 768; i += 512) {
        int r = i >> 5, cc = i & 31;
        *reinterpret_cast<uint4*>(&Vl[r * VSTR + cc * 8]) =
            *reinterpret_cast<const uint4*>(vp + r * NN + cc * 8);
    }

    // Q fragment; g==3 chunk (d=24..31) zero
    bf16x8 qf[2];
    #pragma unroll
    for (int t = 0; t < 2; ++t) {
        bf16x8 z = {};
        qf[t] = (g == 3) ? z : *reinterpret_cast<const bf16x8*>(
            qp + (w * 32 + t * 16 + lq) * HD + g * 8);
    }

    bf16x8 vones, vzero = {};
    {
        uint4 u = {0x3F803F80u, 0x3F803F80u, 0x3F803F80u, 0x3F803F80u};
        vones = *reinterpret_cast<bf16x8*>(&u);
    }

    __syncthreads();

    f32x4 oacc[2][2];                  // [dt][t]; d=24 row of dt=1 = P row-sum
    #pragma unroll
    for (int dt = 0; dt < 2; ++dt)
        #pragma unroll
        for (int t = 0; t < 2; ++t)
            oacc[dt][t] = (f32x4){0.f, 0.f, 0.f, 0.f};

    for (int kt = 0; kt < 4; ++kt) {
        #pragma unroll
        for (int t = 0; t < 2; ++t) {
            // ---- acc init = rel + mask (fragment-ordered, contiguous loads)
            int boff = ((kt * 2 + t) << 10) + (l << 2);
            const unsigned short* rbase = rpw + boff;
            const unsigned short* mbase = mpw + boff;
            f32x4 acc[4];
            #pragma unroll
            for (int f = 0; f < 4; ++f) {
                uint2 rv = *reinterpret_cast<const uint2*>(rbase + (f << 8));
                uint2 mv = *reinterpret_cast<const uint2*>(mbase + (f << 8));
                acc[f][0] = __uint_as_float(rv.x << 16) + __uint_as_float(mv.x << 16);
                acc[f][1] = __uint_as_float(rv.x & 0xffff0000u) + __uint_as_float(mv.x & 0xffff0000u);
                acc[f][2] = __uint_as_float(rv.y << 16) + __uint_as_float(mv.y << 16);
                acc[f][3] = __uint_as_float(rv.y & 0xffff0000u) + __uint_as_float(mv.y & 0xffff0000u);
            }
            #pragma unroll
            for (int f = 0; f < 4; ++f) {
                bf16x8 kf = *reinterpret_cast<const bf16x8*>(
                    &Kl[(kt * 64 + f * 16 + lq) * KSTR + g * 8]);
                acc[f] = __builtin_amdgcn_mfma_f32_16x16x32_bf16(kf, qf[t], acc[f], 0, 0, 0);
            }

            // ---- P = exp2(S) directly (no max shift; scores bounded)
            #pragma unroll
            for (int f = 0; f < 4; ++f)
                #pragma unroll
                for (int jr = 0; jr < 4; ++jr)
                    acc[f][jr] = exp2f(acc[f][jr]);

            // ---- PV directly from registers (permutation makes k contiguous)
            #pragma unroll
            for (int k2 = 0; k2 < 2; ++k2) {
                uint4 pk;
                pk.x = pkbf(acc[2 * k2][0], acc[2 * k2][1]);
                pk.y = pkbf(acc[2 * k2][2], acc[2 * k2][3]);
                pk.z = pkbf(acc[2 * k2 + 1][0], acc[2 * k2 + 1][1]);
                pk.w = pkbf(acc[2 * k2 + 1][2], acc[2 * k2 + 1][3]);
                bf16x8 bfrag = *reinterpret_cast<bf16x8*>(&pk);
                #pragma unroll
                for (int dt = 0; dt < 2; ++dt) {
                    int vrow = dt * 16 + lq;
                    bf16x8 av;
                    if (vrow < 24)
                        av = *reinterpret_cast<const bf16x8*>(
                            &Vl[vrow * VSTR + kt * 64 + k2 * 32 + g * 8]);
                    else
                        av = (vrow == 24) ? vones : vzero;
                    oacc[dt][t] = __builtin_amdgcn_mfma_f32_16x16x32_bf16(
                        av, bfrag, oacc[dt][t], 0, 0, 0);
                }
            }
        }
    }

    // ---- epilogue: s = ones-row (d=24 -> lane 32+lq, jr 0 of oacc[1])
    #pragma unroll
    for (int t = 0; t < 2; ++t) {
        float sv = __shfl(oacc[1][t][0], 32 + lq);
        float inv = 1.0f / sv;
        int qg = b * NN + w * 32 + t * 16 + lq;
        unsigned short* op = ab + (size_t)qg * CC + h * HD;
        #pragma unroll
        for (int dt = 0; dt < 2; ++dt) {
            int d0 = dt * 16 + g * 4;
            if (d0 < HD) {
                uint2 pk;
                pk.x = pkbf(oacc[dt][t][0] * inv, oacc[dt][t][1] * inv);
                pk.y = pkbf(oacc[dt][t][2] * inv, oacc[dt][t][3] * inv);
                *reinterpret_cast<uint2*>(op + d0) = pk;
            }
        }
    }
}

// ---------------------------------------------------------------------------
// Kernel 3: out = ab(bf16) @ proj_w^T + proj_b. BK=96 split (r16 verbatim).
// ---------------------------------------------------------------------------
#define PSTRIDE 104   // 96 cols + pad

__global__ __launch_bounds__(256) void proj_mfma_kernel(
    const unsigned short* __restrict__ ap, const float* __restrict__ wp,
    const float* __restrict__ bias, float* __restrict__ out)
{
    __shared__ __align__(16) unsigned short Xs[128 * PSTRIDE];
    __shared__ __align__(16) unsigned short Ws[64 * PSTRIDE];

    const int tid = threadIdx.x;
    const int wgid = blockIdx.x;                  // 768 = 8 XCD * 96
    const int xcd = wgid & 7;
    const int j = wgid >> 3;
    const int bm = (xcd * 32 + (j & 31)) * 128;
    const int bn = (j >> 5) * 64;

    const int w = tid >> 6, l = tid & 63, lq = l & 15, g = l >> 4;
    const int wm = w >> 1, wn = w & 1;

    f32x4 acc[4][2];
    #pragma unroll
    for (int s = 0; s < 4; ++s)
        #pragma unroll
        for (int t = 0; t < 2; ++t)
            acc[s][t] = (f32x4){0.f, 0.f, 0.f, 0.f};

    #pragma unroll
    for (int kh = 0; kh < 2; ++kh) {
        {
            const unsigned short* src = ap + (size_t)(bm + (tid >> 1)) * 192 + kh * 96 + (tid & 1) * 48;
            unsigned short* dst = &Xs[(tid >> 1) * PSTRIDE + (tid & 1) * 48];
            #pragma unroll
            for (int i = 0; i < 6; ++i)
                *reinterpret_cast<uint4*>(dst + i * 8) =
                    *reinterpret_cast<const uint4*>(src + i * 8);
        }
        {
            const float* src = wp + (size_t)(bn + (tid >> 2)) * 192 + kh * 96 + (tid & 3) * 24;
            unsigned short* dst = &Ws[(tid >> 2) * PSTRIDE + (tid & 3) * 24];
            #pragma unroll
            for (int i = 0; i < 3; ++i) {
                float4 a = *reinterpret_cast<const float4*>(src + i * 8);
                float4 b = *reinterpret_cast<const float4*>(src + i * 8 + 4);
                uint4 o;
                o.x = pkbf(a.x, a.y); o.y = pkbf(a.z, a.w);
                o.z = pkbf(b.x, b.y); o.w = pkbf(b.z, b.w);
                *reinterpret_cast<uint4*>(dst + i * 8) = o;
            }
        }
        __syncthreads();

        #pragma unroll
        for (int kk = 0; kk < 3; ++kk) {
            bf16x8 b0 = *reinterpret_cast<const bf16x8*>(
                &Ws[(wn * 32 + lq) * PSTRIDE + kk * 32 + g * 8]);
            bf16x8 b1 = *reinterpret_cast<const bf16x8*>(
                &Ws[(wn * 32 + 16 + lq) * PSTRIDE + kk * 32 + g * 8]);
            #pragma unroll
            for (int s = 0; s < 4; ++s) {
                bf16x8 a = *reinterpret_cast<const bf16x8*>(
                    &Xs[(wm * 64 + s * 16 + lq) * PSTRIDE + kk * 32 + g * 8]);
                acc[s][0] = __builtin_amdgcn_mfma_f32_16x16x32_bf16(a, b0, acc[s][0], 0, 0, 0);
                acc[s][1] = __builtin_amdgcn_mfma_f32_16x16x32_bf16(a, b1, acc[s][1], 0, 0, 0);
            }
        }
        __syncthreads();
    }

    #pragma unroll
    for (int s = 0; s < 4; ++s) {
        #pragma unroll
        for (int jr = 0; jr < 4; ++jr) {
            int m = bm + wm * 64 + s * 16 + g * 4 + jr;
            #pragma unroll
            for (int t = 0; t < 2; ++t) {
                int c = bn + wn * 32 + t * 16 + lq;
                out[(size_t)m * 192 + c] = acc[s][t][jr] + bias[c];
            }
        }
    }
}

extern "C" void kernel_launch(void* const* d_in, const int* in_sizes, int n_in,
                              void* d_out, int out_size, void* d_ws, size_t ws_size,
                              hipStream_t stream) {
    const float* x      = (const float*)d_in[0];
    const float* rel    = (const float*)d_in[1];
    const float* maskp  = (const float*)d_in[2];
    const float* qkv_w  = (const float*)d_in[3];
    const float* proj_w = (const float*)d_in[4];
    const float* proj_b = (const float*)d_in[5];
    float* out = (float*)d_out;

    unsigned char* wsb = (unsigned char*)d_ws;
    size_t off = 0;
    unsigned short* qbp   = (unsigned short*)(wsb + off); off += QB_BYTES;
    unsigned short* kbp   = (unsigned short*)(wsb + off); off += QB_BYTES;
    unsigned short* vtp   = (unsigned short*)(wsb + off); off += QB_BYTES;
    unsigned short* abp   = (unsigned short*)(wsb + off); off += AB_BYTES;
    unsigned short* biasf = (unsigned short*)(wsb + off); off += BIASF_BYTES;

    qkv_bias_kernel<<<2688, 256, 0, stream>>>(x, qkv_w, rel, maskp,
                                              qbp, kbp, vtp, biasf);
    attn_mfma_kernel<<<1024, 512, 0, stream>>>(qbp, kbp, vtp, biasf, abp);
    proj_mfma_kernel<<<768, 256, 0, stream>>>(abp, proj_w, proj_b, out);
}

// Round 21
// 73.320 us; speedup vs baseline: 1.0351x; 1.0351x over previous
//
#include <hip/hip_runtime.h>
#include <hip/hip_bf16.h>

#define BB 128
#define NN 256
#define CC 192
#define HH 8
#define HD 24
#define NWIN 16

typedef __bf16 bf16x8 __attribute__((ext_vector_type(8)));
typedef float f32x4 __attribute__((ext_vector_type(4)));

#define QB_BYTES (size_t)(BB * HH * NN * HD * 2)    // 12,582,912 (unpadded)
#define AB_BYTES (size_t)(BB * NN * CC * 2)         // 12,582,912
#define BIAS_BYTES (size_t)(128 * NN * NN * 2)      // 16,777,216

#define L2E 1.4426950408889634f

// hardware bf16 converts (v_cvt_pk_bf16_f32 / scalar cvt)
__device__ inline unsigned int pkbf(float a, float b) {
    __hip_bfloat162 h = __float22bfloat162_rn(float2{a, b});
    return *reinterpret_cast<unsigned int*>(&h);
}
__device__ inline unsigned short sbf(float a) {
    __hip_bfloat16 h = __float2bfloat16(a);
    return *reinterpret_cast<unsigned short*>(&h);
}

// ---------------------------------------------------------------------------
// Kernel 1 (fused, r16 verbatim — best measured config, 73.5us total):
// blocks [0,2304) = qkv GEMM (BK=64, BN=64, LDS 27.6KB -> 5 blocks/CU,
// coalesced idx-linear staging); [2304,4352) = combined bias16 backfill.
// ---------------------------------------------------------------------------
#define XSTR 72    // 64 cols + 8 pad (144B rows; 2-way LDS aliasing = free)

__global__ __launch_bounds__(256) void qkv_bias_kernel(
    const float* __restrict__ x, const float* __restrict__ wq,
    const float* __restrict__ rel, const float* __restrict__ maskp,
    unsigned short* __restrict__ qb, unsigned short* __restrict__ kb,
    unsigned short* __restrict__ vt, unsigned short* __restrict__ bias16)
{
    __shared__ __align__(16) unsigned short Xs[128 * XSTR];  // 18432B (reused U/T)
    __shared__ __align__(16) unsigned short Ws[64 * XSTR];   // 9216B

    const int tid = threadIdx.x;
    const int wgid = blockIdx.x;

    if (wgid >= 2304) {
        // ---- bias branch: 4 ushort4 units per thread (fully coalesced)
        int idx0 = (wgid - 2304) * 256 + tid;
        #pragma unroll
        for (int u = 0; u < 4; ++u) {
            int idx = idx0 + u * 524288;
            int c = idx >> 14;
            int rem = idx & 16383;
            int qrow = rem >> 6;
            int k4 = rem & 63;
            int h = c >> 4, wi = c & 15;
            float4 rv = *reinterpret_cast<const float4*>(
                rel + ((size_t)h * NN + qrow) * NN + k4 * 4);
            float4 mv = *reinterpret_cast<const float4*>(
                maskp + ((size_t)wi * NN + qrow) * NN + k4 * 4);
            uint2 o;
            o.x = pkbf((rv.x + mv.x) * L2E, (rv.y + mv.y) * L2E);
            o.y = pkbf((rv.z + mv.z) * L2E, (rv.w + mv.w) * L2E);
            *reinterpret_cast<uint2*>(
                bias16 + ((size_t)c << 16) + qrow * NN + k4 * 4) = o;
        }
        return;
    }

    // ---- qkv branch
    const int q = wgid;                           // 2304 = 8 XCD * 288
    const int xcd = q & 7;
    const int j = q >> 3;
    const int bm = (xcd * 32 + (j & 31)) * 128;
    const int bn = (j >> 5) * 64;

    const int w = tid >> 6, l = tid & 63, lq = l & 15, g = l >> 4;
    const int wm = w >> 1, wn = w & 1;

    f32x4 acc[4][2];
    #pragma unroll
    for (int s = 0; s < 4; ++s)
        #pragma unroll
        for (int t = 0; t < 2; ++t)
            acc[s][t] = (f32x4){0.f, 0.f, 0.f, 0.f};

    #pragma unroll
    for (int kh = 0; kh < 3; ++kh) {
        // stage X (coalesced): 2048 float4/stage, 8/thread; 16 lanes per row
        #pragma unroll
        for (int i = 0; i < 8; ++i) {
            int idx = i * 256 + tid;
            int row = idx >> 4, c4 = idx & 15;
            float4 v = *reinterpret_cast<const float4*>(
                x + (size_t)(bm + row) * 192 + kh * 64 + c4 * 4);
            uint2 o;
            o.x = pkbf(v.x, v.y);
            o.y = pkbf(v.z, v.w);
            *reinterpret_cast<uint2*>(&Xs[row * XSTR + c4 * 4]) = o;
        }
        // stage W (coalesced): 1024 float4/stage, 4/thread
        #pragma unroll
        for (int i = 0; i < 4; ++i) {
            int idx = i * 256 + tid;
            int row = idx >> 4, c4 = idx & 15;
            float4 v = *reinterpret_cast<const float4*>(
                wq + (size_t)(bn + row) * 192 + kh * 64 + c4 * 4);
            uint2 o;
            o.x = pkbf(v.x, v.y);
            o.y = pkbf(v.z, v.w);
            *reinterpret_cast<uint2*>(&Ws[row * XSTR + c4 * 4]) = o;
        }
        __syncthreads();

        #pragma unroll
        for (int kk = 0; kk < 2; ++kk) {
            bf16x8 b0 = *reinterpret_cast<const bf16x8*>(
                &Ws[(wn * 32 + lq) * XSTR + kk * 32 + g * 8]);
            bf16x8 b1 = *reinterpret_cast<const bf16x8*>(
                &Ws[(wn * 32 + 16 + lq) * XSTR + kk * 32 + g * 8]);
            #pragma unroll
            for (int s = 0; s < 4; ++s) {
                bf16x8 a = *reinterpret_cast<const bf16x8*>(
                    &Xs[(wm * 64 + s * 16 + lq) * XSTR + kk * 32 + g * 8]);
                acc[s][0] = __builtin_amdgcn_mfma_f32_16x16x32_bf16(a, b0, acc[s][0], 0, 0, 0);
                acc[s][1] = __builtin_amdgcn_mfma_f32_16x16x32_bf16(a, b1, acc[s][1], 0, 0, 0);
            }
        }
        __syncthreads();   // done reading this stage (also guards Xs reuse)
    }

    const int t3 = bn / 192;          // tile is pure q (0), k (1) or v (2)
    const int bnm = bn - t3 * 192;    // 0, 64, 128
    const int bbi = bm >> 8;

    if (t3 < 2) {
        // ---- path A: U[m_local][c_local], stride 72 (fills Xs exactly)
        // q pre-scaled into exp2 domain: 24^-0.5 * log2(e)
        const float sc = (t3 == 0) ? 0.29448889f : 1.0f;
        #pragma unroll
        for (int s = 0; s < 4; ++s)
            #pragma unroll
            for (int t = 0; t < 2; ++t)
                #pragma unroll
                for (int jr = 0; jr < 4; ++jr) {
                    int ml = wm * 64 + s * 16 + g * 4 + jr;
                    int cl = wn * 32 + t * 16 + lq;
                    Xs[ml * 72 + cl] = sbf(acc[s][t][jr] * sc);
                }
        __syncthreads();
        unsigned short* dstb = (t3 == 0) ? qb : kb;
        #pragma unroll
        for (int i = 0; i < 8; ++i) {
            int idx = i * 256 + tid;
            int row = idx >> 4, quad = (idx & 15) * 4;
            int cg = bnm + quad;
            int h = cg / 24;
            int d = cg - h * 24;
            int m = bm + row;
            int n = m & 255;
            uint2 v = *reinterpret_cast<const uint2*>(&Xs[row * 72 + quad]);
            *reinterpret_cast<uint2*>(
                &dstb[(((size_t)(bbi * 8 + h) * 256) + n) * 24 + d]) = v;
        }
    } else {
        // ---- path B: T[c_local][m_local], stride 136 (8704 <= 9216 Xs)
        #pragma unroll
        for (int s = 0; s < 4; ++s)
            #pragma unroll
            for (int t = 0; t < 2; ++t) {
                int cl = wn * 32 + t * 16 + lq;
                int m0 = wm * 64 + s * 16 + g * 4;
                uint2 pk2;
                pk2.x = pkbf(acc[s][t][0], acc[s][t][1]);
                pk2.y = pkbf(acc[s][t][2], acc[s][t][3]);
                *reinterpret_cast<uint2*>(&Xs[cl * 136 + m0]) = pk2;
            }
        __syncthreads();
        const int n0 = bm & 255;
        #pragma unroll
        for (int i = 0; i < 4; ++i) {
            int idx = i * 256 + tid;
            int row = idx >> 4, q8 = (idx & 15) * 8;
            int cg = bnm + row;
            int h = cg / 24, d = cg - h * 24;
            uint4 v = *reinterpret_cast<const uint4*>(&Xs[row * 136 + q8]);
            *reinterpret_cast<uint4*>(
                &vt[((size_t)((bbi * 8 + h) * 24) + d) * 256 + n0 + q8]) = v;
        }
    }
}

// ---------------------------------------------------------------------------
// Kernel 2: flash MFMA attention, NO-MAX softmax (r16 structure).
// r21: kt loop fully unrolled so the compiler can hoist the 8 iterations'
// independent bias C-init loads across the MFMA/exp2 chains (its regalloc
// heuristics bound the depth; spill tripwire = WRITE_SIZE in post-mortem).
// ---------------------------------------------------------------------------
#define KSTR 40
#define VSTR 264

__global__ __launch_bounds__(512) void attn_mfma_kernel(
    const unsigned short* __restrict__ qb, const unsigned short* __restrict__ kb,
    const unsigned short* __restrict__ vt,
    const unsigned short* __restrict__ bias16,
    unsigned short* __restrict__ ab)
{
    __shared__ __align__(16) unsigned short Kl[NN * KSTR];    // 20480 B (permuted)
    __shared__ __align__(16) unsigned short Vl[24 * VSTR];    // 12672 B

    const int tid = threadIdx.x;
    const int w  = tid >> 6;
    const int l  = tid & 63;
    const int lq = l & 15;
    const int g  = l >> 4;
    const int wgid = blockIdx.x;
    const int c = wgid & 127;          // bias combo = h*16 + wi (XCD-local)
    const int j = wgid >> 7;
    const int h = c >> 4;
    const int b = (c & 15) + (j << 4);

    const unsigned short* kp = kb + (size_t)(b * HH + h) * NN * HD;
    const unsigned short* vp = vt + (size_t)(b * HH + h) * HD * NN;
    const unsigned short* qp = qb + (size_t)(b * HH + h) * NN * HD;
    const unsigned short* bp = bias16 + ((size_t)c << 16);

    // stage K permuted; d=24..31 chunk zero-filled (unpadded source)
    for (int i = tid; i < 1024; i += 512) {
        int r = i >> 2, cc = i & 3;
        int pr = ((r >> 5) << 5) + (((r >> 2) & 1) << 4) + (((r >> 3) & 3) << 2) + (r & 3);
        uint4 val = {0u, 0u, 0u, 0u};
        if (cc < 3)
            val = *reinterpret_cast<const uint4*>(kp + r * HD + cc * 8);
        *reinterpret_cast<uint4*>(&Kl[pr * KSTR + cc * 8]) = val;
    }
    // stage V^T rows 0..23 (natural order)
    for (int i = tid; i < 768; i += 512) {
        int r = i >> 5, cc = i & 31;
        *reinterpret_cast<uint4*>(&Vl[r * VSTR + cc * 8]) =
            *reinterpret_cast<const uint4*>(vp + r * NN + cc * 8);
    }

    // Q fragment; g==3 chunk (d=24..31) zero
    bf16x8 qf[2];
    #pragma unroll
    for (int t = 0; t < 2; ++t) {
        bf16x8 z = {};
        qf[t] = (g == 3) ? z : *reinterpret_cast<const bf16x8*>(
            qp + (w * 32 + t * 16 + lq) * HD + g * 8);
    }

    const unsigned short* bq0 = bp + (size_t)(w * 32 + lq) * NN;
    const unsigned short* bq1 = bp + (size_t)(w * 32 + 16 + lq) * NN;

    bf16x8 vones, vzero = {};
    {
        uint4 u = {0x3F803F80u, 0x3F803F80u, 0x3F803F80u, 0x3F803F80u};
        vones = *reinterpret_cast<bf16x8*>(&u);
    }

    __syncthreads();

    f32x4 oacc[2][2];                  // [dt][t]; d=24 row of dt=1 = P row-sum
    #pragma unroll
    for (int dt = 0; dt < 2; ++dt)
        #pragma unroll
        for (int t = 0; t < 2; ++t)
            oacc[dt][t] = (f32x4){0.f, 0.f, 0.f, 0.f};

    #pragma unroll
    for (int kt = 0; kt < 4; ++kt) {
        #pragma unroll
        for (int t = 0; t < 2; ++t) {
            const unsigned short* bq = t ? bq1 : bq0;

            // ---- acc init = bias (permuted k mapping), then QK^T MFMA
            f32x4 acc[4];
            #pragma unroll
            for (int f = 0; f < 4; ++f) {
                uint2 bv = *reinterpret_cast<const uint2*>(
                    bq + kt * 64 + ((f >> 1) << 5) + (g << 3) + ((f & 1) << 2));
                acc[f][0] = __uint_as_float(bv.x << 16);
                acc[f][1] = __uint_as_float(bv.x & 0xffff0000u);
                acc[f][2] = __uint_as_float(bv.y << 16);
                acc[f][3] = __uint_as_float(bv.y & 0xffff0000u);
            }
            #pragma unroll
            for (int f = 0; f < 4; ++f) {
                bf16x8 kf = *reinterpret_cast<const bf16x8*>(
                    &Kl[(kt * 64 + f * 16 + lq) * KSTR + g * 8]);
                acc[f] = __builtin_amdgcn_mfma_f32_16x16x32_bf16(kf, qf[t], acc[f], 0, 0, 0);
            }

            // ---- P = exp2(S) directly (no max shift; scores bounded)
            #pragma unroll
            for (int f = 0; f < 4; ++f)
                #pragma unroll
                for (int jr = 0; jr < 4; ++jr)
                    acc[f][jr] = exp2f(acc[f][jr]);

            // ---- PV directly from registers (permutation makes k contiguous)
            #pragma unroll
            for (int k2 = 0; k2 < 2; ++k2) {
                uint4 pk;
                pk.x = pkbf(acc[2 * k2][0], acc[2 * k2][1]);
                pk.y = pkbf(acc[2 * k2][2], acc[2 * k2][3]);
                pk.z = pkbf(acc[2 * k2 + 1][0], acc[2 * k2 + 1][1]);
                pk.w = pkbf(acc[2 * k2 + 1][2], acc[2 * k2 + 1][3]);
                bf16x8 bfrag = *reinterpret_cast<bf16x8*>(&pk);
                #pragma unroll
                for (int dt = 0; dt < 2; ++dt) {
                    int vrow = dt * 16 + lq;
                    bf16x8 av;
                    if (vrow < 24)
                        av = *reinterpret_cast<const bf16x8*>(
                            &Vl[vrow * VSTR + kt * 64 + k2 * 32 + g * 8]);
                    else
                        av = (vrow == 24) ? vones : vzero;
                    oacc[dt][t] = __builtin_amdgcn_mfma_f32_16x16x32_bf16(
                        av, bfrag, oacc[dt][t], 0, 0, 0);
                }
            }
        }
    }

    // ---- epilogue: s = ones-row (d=24 -> lane 32+lq, jr 0 of oacc[1])
    #pragma unroll
    for (int t = 0; t < 2; ++t) {
        float sv = __shfl(oacc[1][t][0], 32 + lq);
        float inv = 1.0f / sv;
        int qg = b * NN + w * 32 + t * 16 + lq;
        unsigned short* op = ab + (size_t)qg * CC + h * HD;
        #pragma unroll
        for (int dt = 0; dt < 2; ++dt) {
            int d0 = dt * 16 + g * 4;
            if (d0 < HD) {
                uint2 pk;
                pk.x = pkbf(oacc[dt][t][0] * inv, oacc[dt][t][1] * inv);
                pk.y = pkbf(oacc[dt][t][2] * inv, oacc[dt][t][3] * inv);
                *reinterpret_cast<uint2*>(op + d0) = pk;
            }
        }
    }
}

// ---------------------------------------------------------------------------
// Kernel 3: out = ab(bf16) @ proj_w^T + proj_b. BK=96 split (r16 verbatim).
// ---------------------------------------------------------------------------
#define PSTRIDE 104   // 96 cols + pad

__global__ __launch_bounds__(256) void proj_mfma_kernel(
    const unsigned short* __restrict__ ap, const float* __restrict__ wp,
    const float* __restrict__ bias, float* __restrict__ out)
{
    __shared__ __align__(16) unsigned short Xs[128 * PSTRIDE];
    __shared__ __align__(16) unsigned short Ws[64 * PSTRIDE];

    const int tid = threadIdx.x;
    const int wgid = blockIdx.x;                  // 768 = 8 XCD * 96
    const int xcd = wgid & 7;
    const int j = wgid >> 3;
    const int bm = (xcd * 32 + (j & 31)) * 128;
    const int bn = (j >> 5) * 64;

    const int w = tid >> 6, l = tid & 63, lq = l & 15, g = l >> 4;
    const int wm = w >> 1, wn = w & 1;

    f32x4 acc[4][2];
    #pragma unroll
    for (int s = 0; s < 4; ++s)
        #pragma unroll
        for (int t = 0; t < 2; ++t)
            acc[s][t] = (f32x4){0.f, 0.f, 0.f, 0.f};

    #pragma unroll
    for (int kh = 0; kh < 2; ++kh) {
        {
            const unsigned short* src = ap + (size_t)(bm + (tid >> 1)) * 192 + kh * 96 + (tid & 1) * 48;
            unsigned short* dst = &Xs[(tid >> 1) * PSTRIDE + (tid & 1) * 48];
            #pragma unroll
            for (int i = 0; i < 6; ++i)
                *reinterpret_cast<uint4*>(dst + i * 8) =
                    *reinterpret_cast<const uint4*>(src + i * 8);
        }
        {
            const float* src = wp + (size_t)(bn + (tid >> 2)) * 192 + kh * 96 + (tid & 3) * 24;
            unsigned short* dst = &Ws[(tid >> 2) * PSTRIDE + (tid & 3) * 24];
            #pragma unroll
            for (int i = 0; i < 3; ++i) {
                float4 a = *reinterpret_cast<const float4*>(src + i * 8);
                float4 b = *reinterpret_cast<const float4*>(src + i * 8 + 4);
                uint4 o;
                o.x = pkbf(a.x, a.y); o.y = pkbf(a.z, a.w);
                o.z = pkbf(b.x, b.y); o.w = pkbf(b.z, b.w);
                *reinterpret_cast<uint4*>(dst + i * 8) = o;
            }
        }
        __syncthreads();

        #pragma unroll
        for (int kk = 0; kk < 3; ++kk) {
            bf16x8 b0 = *reinterpret_cast<const bf16x8*>(
                &Ws[(wn * 32 + lq) * PSTRIDE + kk * 32 + g * 8]);
            bf16x8 b1 = *reinterpret_cast<const bf16x8*>(
                &Ws[(wn * 32 + 16 + lq) * PSTRIDE + kk * 32 + g * 8]);
            #pragma unroll
            for (int s = 0; s < 4; ++s) {
                bf16x8 a = *reinterpret_cast<const bf16x8*>(
                    &Xs[(wm * 64 + s * 16 + lq) * PSTRIDE + kk * 32 + g * 8]);
                acc[s][0] = __builtin_amdgcn_mfma_f32_16x16x32_bf16(a, b0, acc[s][0], 0, 0, 0);
                acc[s][1] = __builtin_amdgcn_mfma_f32_16x16x32_bf16(a, b1, acc[s][1], 0, 0, 0);
            }
        }
        __syncthreads();
    }

    #pragma unroll
    for (int s = 0; s < 4; ++s) {
        #pragma unroll
        for (int jr = 0; jr < 4; ++jr) {
            int m = bm + wm * 64 + s * 16 + g * 4 + jr;
            #pragma unroll
            for (int t = 0; t < 2; ++t) {
                int c = bn + wn * 32 + t * 16 + lq;
                out[(size_t)m * 192 + c] = acc[s][t][jr] + bias[c];
            }
        }
    }
}

extern "C" void kernel_launch(void* const* d_in, const int* in_sizes, int n_in,
                              void* d_out, int out_size, void* d_ws, size_t ws_size,
                              hipStream_t stream) {
    const float* x      = (const float*)d_in[0];
    const float* rel    = (const float*)d_in[1];
    const float* maskp  = (const float*)d_in[2];
    const float* qkv_w  = (const float*)d_in[3];
    const float* proj_w = (const float*)d_in[4];
    const float* proj_b = (const float*)d_in[5];
    float* out = (float*)d_out;

    unsigned char* wsb = (unsigned char*)d_ws;
    size_t off = 0;
    unsigned short* qbp    = (unsigned short*)(wsb + off); off += QB_BYTES;
    unsigned short* kbp    = (unsigned short*)(wsb + off); off += QB_BYTES;
    unsigned short* vtp    = (unsigned short*)(wsb + off); off += QB_BYTES;
    unsigned short* abp    = (unsigned short*)(wsb + off); off += AB_BYTES;
    unsigned short* bias16 = (unsigned short*)(wsb + off); off += BIAS_BYTES;

    qkv_bias_kernel<<<4352, 256, 0, stream>>>(x, qkv_w, rel, maskp,
                                              qbp, kbp, vtp, bias16);
    attn_mfma_kernel<<<1024, 512, 0, stream>>>(qbp, kbp, vtp, bias16, abp);
    proj_mfma_kernel<<<768, 256, 0, stream>>>(abp, proj_w, proj_b, out);
}